// Round 6
// baseline (284.892 us; speedup 1.0000x reference)
//
#include <hip/hip_runtime.h>
#include <math.h>

constexpr float WLIM = 5000.0f;
constexpr double RIDGE = 1e-7;

// Read this wave's XCD id (0-7) from the hardware register. HW-verified on
// MI355X (learn_hip m09). Constant for a workgroup's lifetime.
static __device__ __forceinline__ int xcc_id() {
    int x;
    asm("s_getreg_b32 %0, hwreg(HW_REG_XCC_ID, 0, 8)" : "=s"(x));
    return x & 7;
}

// ---------------- Kernel 1: build 8 per-node linked lists (one per XCD) ----------------
// head[n*8+xcc] is only ever atomically touched from XCD xcc -> the exchange can
// run at WORKGROUP scope, which lowers to an sc1-free L2-local atomic (no fabric
// message). nxt stores remain coalesced.
__global__ __launch_bounds__(256) void k_build(const int* __restrict__ row,
                                               int* __restrict__ head,
                                               int* __restrict__ nxt, int nE4, int nE) {
    const int xc = xcc_id();
    int t = blockIdx.x * blockDim.x + threadIdx.x;
    if (t < nE4) {
        int4 r4 = ((const int4*)row)[t];
        int e0 = t * 4;
        int4 n4;
        n4.x = __hip_atomic_exchange(&head[r4.x * 8 + xc], e0 + 0, __ATOMIC_RELAXED, __HIP_MEMORY_SCOPE_WORKGROUP);
        n4.y = __hip_atomic_exchange(&head[r4.y * 8 + xc], e0 + 1, __ATOMIC_RELAXED, __HIP_MEMORY_SCOPE_WORKGROUP);
        n4.z = __hip_atomic_exchange(&head[r4.z * 8 + xc], e0 + 2, __ATOMIC_RELAXED, __HIP_MEMORY_SCOPE_WORKGROUP);
        n4.w = __hip_atomic_exchange(&head[r4.w * 8 + xc], e0 + 3, __ATOMIC_RELAXED, __HIP_MEMORY_SCOPE_WORKGROUP);
        ((int4*)nxt)[t] = n4;
    }
    // scalar tail
    int tail0 = nE4 * 4;
    int i = tail0 + t;
    if (t < (nE - tail0)) {
        int r = row[i];
        nxt[i] = __hip_atomic_exchange(&head[r * 8 + xc], i, __ATOMIC_RELAXED, __HIP_MEMORY_SCOPE_WORKGROUP);
    }
}

// ---------------- Kernel 2: traverse 8 chains interleaved, accumulate, f64 Cholesky ----
__global__ __launch_bounds__(256) void k_node(const float2* __restrict__ pos,
                                              const int* __restrict__ col,
                                              const int* __restrict__ head,
                                              const int* __restrict__ nxt,
                                              float* __restrict__ rec, int nN) {
    int n = blockIdx.x * blockDim.x + threadIdx.x;
    if (n >= nN) return;
    float2 pr = pos[n];
    float m[15];
    #pragma unroll
    for (int i = 0; i < 15; ++i) m[i] = 0.0f;

    // load the 8 chain heads (two int4 loads)
    int e[8];
    {
        const int4* hb = (const int4*)(head + (size_t)n * 8);
        int4 h0 = hb[0];
        int4 h1 = hb[1];
        e[0] = h0.x; e[1] = h0.y; e[2] = h0.z; e[3] = h0.w;
        e[4] = h1.x; e[5] = h1.y; e[6] = h1.z; e[7] = h1.w;
    }
    // chase all 8 chains round-robin: up to 16 independent gathers in flight
    bool any = true;
    while (any) {
        any = false;
        int cs[8], nx[8];
        #pragma unroll
        for (int k = 0; k < 8; ++k) {
            if (e[k] >= 0) { cs[k] = col[e[k]]; nx[k] = nxt[e[k]]; }
        }
        #pragma unroll
        for (int k = 0; k < 8; ++k) {
            if (e[k] >= 0) {
                float2 pc = pos[cs[k]];
                float x = pc.x - pr.x;
                float y = pc.y - pr.y;
                float xy = x * y, xx = x * x, yy = y * y;
                m[0]  += x * x;   m[1]  += x * y;   m[2]  += x * xy;  m[3]  += x * xx;  m[4]  += x * yy;
                m[5]  += y * y;   m[6]  += y * xy;  m[7]  += y * xx;  m[8]  += y * yy;
                m[9]  += xy * xy; m[10] += xy * xx; m[11] += xy * yy;
                m[12] += xx * xx; m[13] += xx * yy;
                m[14] += yy * yy;
                e[k] = nx[k];
                any = true;
            }
        }
    }

    double A[5][5];
    {
        int idx = 0;
        #pragma unroll
        for (int i = 0; i < 5; ++i) {
            #pragma unroll
            for (int j = i; j < 5; ++j) {
                double v = (double)m[idx++];
                A[i][j] = v;
                A[j][i] = v;
            }
        }
    }
    #pragma unroll
    for (int i = 0; i < 5; ++i) A[i][i] += RIDGE;

    // Cholesky (static indices only)
    #pragma unroll
    for (int k = 0; k < 5; ++k) {
        double d = A[k][k];
        d = sqrt(fmax(d, 1e-300));
        A[k][k] = d;
        double inv = 1.0 / d;
        #pragma unroll
        for (int i = k + 1; i < 5; ++i) A[i][k] *= inv;
        #pragma unroll
        for (int j = k + 1; j < 5; ++j) {
            #pragma unroll
            for (int i = j; i < 5; ++i) A[i][j] -= A[i][k] * A[j][k];
        }
    }
    // b = [0,0,0,2,2]; L y = b
    double b[5] = {0.0, 0.0, 0.0, 2.0, 2.0};
    double y[5];
    #pragma unroll
    for (int i = 0; i < 5; ++i) {
        double sv = b[i];
        #pragma unroll
        for (int k = 0; k < 5; ++k) {
            if (k < i) sv -= A[i][k] * y[k];
        }
        y[i] = sv / A[i][i];
    }
    // L^T x = y
    double xs[5];
    #pragma unroll
    for (int ii = 4; ii >= 0; --ii) {
        double sv = y[ii];
        #pragma unroll
        for (int k = 0; k < 5; ++k) {
            if (k > ii) sv -= A[k][ii] * xs[k];
        }
        xs[ii] = sv / A[ii][ii];
    }

    float4* rb = (float4*)(rec + (size_t)n * 8);
    rb[0] = make_float4((float)xs[0], (float)xs[1], (float)xs[2], (float)xs[3]);
    rb[1] = make_float4((float)xs[4], pr.x, pr.y, 0.0f);
}

// ---------------- Kernel 3: per-edge weight = <C[row], H>, clipped ----------------
__global__ __launch_bounds__(256) void k_weights(const float2* __restrict__ pos,
                                                 const int* __restrict__ row,
                                                 const int* __restrict__ col,
                                                 const float* __restrict__ rec,
                                                 float* __restrict__ out,
                                                 int nE) {
    int e = blockIdx.x * blockDim.x + threadIdx.x;
    if (e >= nE) return;
    int r = row[e];
    int c = col[e];
    const float4* rb = (const float4*)(rec + (size_t)r * 8);
    float4 r0 = rb[0];               // C0..C3
    float4 r1 = rb[1];               // C4, pos_r.x, pos_r.y, pad
    float2 pc = pos[c];
    float x = pc.x - r1.y;
    float y = pc.y - r1.z;
    float w = r0.x * x + r0.y * y + r0.z * (x * y) + r0.w * (x * x) + r1.x * (y * y);
    w = fminf(fmaxf(w, -WLIM), WLIM);
    out[e] = w;
}

extern "C" void kernel_launch(void* const* d_in, const int* in_sizes, int n_in,
                              void* d_out, int out_size, void* d_ws, size_t ws_size,
                              hipStream_t stream) {
    const float2* pos = (const float2*)d_in[0];
    const int* ei = (const int*)d_in[1];
    const int nN = in_sizes[0] / 2;   // (N,2) f32
    const int nE = in_sizes[1] / 2;   // (2,E) int32
    const int* row = ei;
    const int* col = ei + nE;

    // workspace: head (nN*8 ints = 3.2MB) + rec (nN*8 floats = 3.2MB)
    int* head = (int*)d_ws;
    float* rec = (float*)(head + (size_t)nN * 8);

    // next[] lives in d_out (nE ints in nE floats); fully consumed by k_node
    // before k_weights overwrites d_out with the result.
    int* nxt = (int*)d_out;
    float* out = (float*)d_out;

    hipMemsetAsync(head, 0xFF, (size_t)nN * 8 * sizeof(int), stream);  // all heads = -1

    const int tb = 256;
    const int nE4 = nE / 4;
    const int bgrid = (nE4 + tb - 1) / tb;
    k_build<<<bgrid, tb, 0, stream>>>(row, head, nxt, nE4, nE);
    k_node<<<(nN + tb - 1) / tb, tb, 0, stream>>>(pos, col, head, nxt, rec, nN);
    k_weights<<<(nE + tb - 1) / tb, tb, 0, stream>>>(pos, row, col, rec, out, nE);
}

// Round 7
// 212.040 us; speedup vs baseline: 1.3436x; 1.3436x over previous
//
#include <hip/hip_runtime.h>
#include <math.h>

constexpr float WLIM = 5000.0f;
constexpr double RIDGE = 1e-7;

#define G 256             // edge-chunk blocks for hist/scatter
#define MAXNB 1024        // max buckets (nN up to 131072)
#define BN 128            // nodes per bucket
#define CAP 6144          // LDS edge capacity per bucket (mean 4096, +32 sigma)

// ---------------- Kernel 1: per-block bucket histogram (LDS int atomics only) ----------------
__global__ __launch_bounds__(1024) void k_hist(const int* __restrict__ row,
                                               int* __restrict__ table,
                                               int nE, int CE, int NB) {
    __shared__ int h[MAXNB];
    const int g = blockIdx.x, tid = threadIdx.x;
    for (int i = tid; i < NB; i += 1024) h[i] = 0;
    __syncthreads();
    int s = g * CE;
    int e_end = min(s + CE, nE);
    for (int i = s + tid; i < e_end; i += 1024)
        atomicAdd(&h[row[i] >> 7], 1);
    __syncthreads();
    for (int i = tid; i < NB; i += 1024) table[(size_t)g * NB + i] = h[i];
}

// ---------------- Kernel 2: scan -> per-(bucket,block) start offsets + bucket bases ----
__global__ __launch_bounds__(1024) void k_scan(int* __restrict__ table,
                                               int* __restrict__ base,
                                               int NB, int nG) {
    __shared__ int tot[MAXNB];
    const int b = threadIdx.x;
    int myTot = 0;
    if (b < NB) {
        int s = 0;
        for (int g = 0; g < nG; ++g) {
            int idx = g * NB + b;          // consecutive b -> coalesced
            int v = table[idx];
            table[idx] = s;
            s += v;
        }
        myTot = s;
        tot[b] = s;
    }
    __syncthreads();
    // Hillis-Steele inclusive scan of tot[0..NB)
    for (int d = 1; d < MAXNB; d <<= 1) {
        int v = 0;
        if (b >= d && b < NB) v = tot[b - d];
        __syncthreads();
        if (b >= d && b < NB) tot[b] += v;
        __syncthreads();
    }
    if (b < NB) {
        int excl = tot[b] - myTot;
        base[b] = excl;
        if (b == NB - 1) base[NB] = tot[b];
        for (int g = 0; g < nG; ++g) table[g * NB + b] += excl;
    }
}

// ---------------- Kernel 3: scatter packed (local_r<<17 | col) into bucket order ----------------
__global__ __launch_bounds__(1024) void k_scatter(const int* __restrict__ row,
                                                  const int* __restrict__ col,
                                                  const int* __restrict__ table,
                                                  unsigned int* __restrict__ sorted,
                                                  int nE, int CE, int NB) {
    __shared__ int cur[MAXNB];
    const int g = blockIdx.x, tid = threadIdx.x;
    for (int i = tid; i < NB; i += 1024) cur[i] = table[(size_t)g * NB + i];
    __syncthreads();
    int s = g * CE;
    int e_end = min(s + CE, nE);
    for (int i = s + tid; i < e_end; i += 1024) {
        int r = row[i];
        int c = col[i];
        int b = r >> 7;
        int p = atomicAdd(&cur[b], 1);
        sorted[p] = ((unsigned)(r & 127) << 17) | (unsigned)c;   // col < 131072
    }
}

// ---------------- Kernel 4: per-bucket LDS counting sort + register accumulation + Cholesky ----
__global__ __launch_bounds__(256) void k_node2(const float2* __restrict__ pos,
                                               const unsigned int* __restrict__ sorted,
                                               const int* __restrict__ base,
                                               float* __restrict__ rec, int nN) {
    __shared__ unsigned int ebuf[CAP];
    __shared__ unsigned int ecol[CAP];
    __shared__ int off[BN + 1];     // exclusive offsets after scan
    __shared__ int cur[BN];
    const int b = blockIdx.x, tid = threadIdx.x;
    const int s = base[b], e = base[b + 1];
    const int cntE = min(e - s, CAP);

    // load packed edges (coalesced)
    for (int i = tid; i < cntE; i += 256) ebuf[i] = sorted[s + i];
    if (tid < BN + 1) off[tid] = 0;
    __syncthreads();
    // count per local node (int LDS atomics, ~cntE total)
    for (int i = tid; i < cntE; i += 256) atomicAdd(&off[(ebuf[i] >> 17) + 1], 1);
    __syncthreads();
    // serial exclusive scan of 128 counters (cheap)
    if (tid == 0) {
        int a = 0;
        #pragma unroll 8
        for (int i = 0; i <= BN; ++i) { a += off[i]; off[i] = a; }
        // off[i] is now inclusive-of-previous: off[0]=0? No: rebuild exclusive below.
    }
    __syncthreads();
    // off[] currently: off[0]=0-count? Fix: recompute properly (off[i] holds prefix including bucket i's count shifted by one slot because counts went to idx+1)
    if (tid < BN) cur[tid] = off[tid];
    __syncthreads();
    // scatter cols into node-sorted order
    for (int i = tid; i < cntE; i += 256) {
        unsigned v = ebuf[i];
        int lr = (int)(v >> 17);
        int p = atomicAdd(&cur[lr], 1);
        ecol[p] = v & 0x1FFFFu;
    }
    __syncthreads();

    if (tid < BN) {
        int n = (b << 7) + tid;
        if (n < nN) {
            float2 pr = pos[n];
            float m[15];
            #pragma unroll
            for (int i = 0; i < 15; ++i) m[i] = 0.0f;
            int j0 = off[tid], j1 = off[tid + 1];
            for (int j = j0; j < j1; ++j) {
                float2 pc = pos[ecol[j]];
                float x = pc.x - pr.x;
                float y = pc.y - pr.y;
                float xy = x * y, xx = x * x, yy = y * y;
                m[0]  += x * x;   m[1]  += x * y;   m[2]  += x * xy;  m[3]  += x * xx;  m[4]  += x * yy;
                m[5]  += y * y;   m[6]  += y * xy;  m[7]  += y * xx;  m[8]  += y * yy;
                m[9]  += xy * xy; m[10] += xy * xx; m[11] += xy * yy;
                m[12] += xx * xx; m[13] += xx * yy;
                m[14] += yy * yy;
            }
            // overflow edges beyond CAP (essentially never taken): scan global tail
            for (int j = CAP; j < e - s; ++j) {
                unsigned v = sorted[s + j];
                if ((int)(v >> 17) == tid) {
                    float2 pc = pos[v & 0x1FFFFu];
                    float x = pc.x - pr.x;
                    float y = pc.y - pr.y;
                    float xy = x * y, xx = x * x, yy = y * y;
                    m[0]  += x * x;   m[1]  += x * y;   m[2]  += x * xy;  m[3]  += x * xx;  m[4]  += x * yy;
                    m[5]  += y * y;   m[6]  += y * xy;  m[7]  += y * xx;  m[8]  += y * yy;
                    m[9]  += xy * xy; m[10] += xy * xx; m[11] += xy * yy;
                    m[12] += xx * xx; m[13] += xx * yy;
                    m[14] += yy * yy;
                }
            }

            double A[5][5];
            {
                int idx = 0;
                #pragma unroll
                for (int i = 0; i < 5; ++i) {
                    #pragma unroll
                    for (int j = i; j < 5; ++j) {
                        double v = (double)m[idx++];
                        A[i][j] = v;
                        A[j][i] = v;
                    }
                }
            }
            #pragma unroll
            for (int i = 0; i < 5; ++i) A[i][i] += RIDGE;

            // Cholesky (static indices only)
            #pragma unroll
            for (int k = 0; k < 5; ++k) {
                double d = A[k][k];
                d = sqrt(fmax(d, 1e-300));
                A[k][k] = d;
                double inv = 1.0 / d;
                #pragma unroll
                for (int i = k + 1; i < 5; ++i) A[i][k] *= inv;
                #pragma unroll
                for (int j = k + 1; j < 5; ++j) {
                    #pragma unroll
                    for (int i = j; i < 5; ++i) A[i][j] -= A[i][k] * A[j][k];
                }
            }
            double bb[5] = {0.0, 0.0, 0.0, 2.0, 2.0};
            double y[5];
            #pragma unroll
            for (int i = 0; i < 5; ++i) {
                double sv = bb[i];
                #pragma unroll
                for (int k = 0; k < 5; ++k) {
                    if (k < i) sv -= A[i][k] * y[k];
                }
                y[i] = sv / A[i][i];
            }
            double xs[5];
            #pragma unroll
            for (int ii = 4; ii >= 0; --ii) {
                double sv = y[ii];
                #pragma unroll
                for (int k = 0; k < 5; ++k) {
                    if (k > ii) sv -= A[k][ii] * xs[k];
                }
                xs[ii] = sv / A[ii][ii];
            }
            float4* rb = (float4*)(rec + (size_t)n * 8);
            rb[0] = make_float4((float)xs[0], (float)xs[1], (float)xs[2], (float)xs[3]);
            rb[1] = make_float4((float)xs[4], pr.x, pr.y, 0.0f);
        }
    }
}

// ---------------- Kernel 5: per-edge weight = <C[row], H>, clipped (overwrites d_out) ----
__global__ __launch_bounds__(256) void k_weights(const float2* __restrict__ pos,
                                                 const int* __restrict__ row,
                                                 const int* __restrict__ col,
                                                 const float* __restrict__ rec,
                                                 float* __restrict__ out,
                                                 int nE) {
    int e = blockIdx.x * blockDim.x + threadIdx.x;
    if (e >= nE) return;
    int r = row[e];
    int c = col[e];
    const float4* rb = (const float4*)(rec + (size_t)r * 8);
    float4 r0 = rb[0];               // C0..C3
    float4 r1 = rb[1];               // C4, pos_r.x, pos_r.y, pad
    float2 pc = pos[c];
    float x = pc.x - r1.y;
    float y = pc.y - r1.z;
    float w = r0.x * x + r0.y * y + r0.z * (x * y) + r0.w * (x * x) + r1.x * (y * y);
    w = fminf(fmaxf(w, -WLIM), WLIM);
    out[e] = w;
}

extern "C" void kernel_launch(void* const* d_in, const int* in_sizes, int n_in,
                              void* d_out, int out_size, void* d_ws, size_t ws_size,
                              hipStream_t stream) {
    const float2* pos = (const float2*)d_in[0];
    const int* ei = (const int*)d_in[1];
    const int nN = in_sizes[0] / 2;   // (N,2) f32
    const int nE = in_sizes[1] / 2;   // (2,E) int32
    const int* row = ei;
    const int* col = ei + nE;

    const int NB = (nN + BN - 1) >> 7;        // buckets of 128 nodes
    const int CE = (nE + G - 1) / G;          // edges per hist/scatter block

    // ws layout: table[G*NB] | base[NB+1] | pad to 16B | rec[nN*8 floats]
    int* table = (int*)d_ws;
    int* base = table + (size_t)G * NB;
    size_t roff = (((size_t)G * NB + NB + 1) + 3) & ~(size_t)3;
    float* rec = (float*)((int*)d_ws + roff);

    unsigned int* sorted = (unsigned int*)d_out;  // consumed by k_node2 before k_weights overwrites
    float* out = (float*)d_out;

    k_hist<<<G, 1024, 0, stream>>>(row, table, nE, CE, NB);
    k_scan<<<1, 1024, 0, stream>>>(table, base, NB, G);
    k_scatter<<<G, 1024, 0, stream>>>(row, col, table, sorted, nE, CE, NB);
    k_node2<<<NB, 256, 0, stream>>>(pos, sorted, base, rec, nN);
    k_weights<<<(nE + 255) / 256, 256, 0, stream>>>(pos, row, col, rec, out, nE);
}

// Round 8
// 119.713 us; speedup vs baseline: 2.3798x; 1.7712x over previous
//
#include <hip/hip_runtime.h>
#include <math.h>

constexpr float WLIM = 5000.0f;
constexpr double RIDGE = 1e-7;

#define G 256             // edge-chunk blocks for hist/scatter (== k_scanA block size)
#define MAXNB 1024        // max buckets (nN up to 131072)
#define BN 128            // nodes per bucket
#define CAP 6144          // LDS edge capacity per bucket (mean 4096, +32 sigma)

// ---------------- Kernel 1: per-block bucket histogram (LDS int atomics only) ----------------
__global__ __launch_bounds__(1024) void k_hist(const int* __restrict__ row,
                                               int* __restrict__ table,
                                               int nE, int CE, int NB) {
    __shared__ int h[MAXNB];
    const int g = blockIdx.x, tid = threadIdx.x;
    for (int i = tid; i < NB; i += 1024) h[i] = 0;
    __syncthreads();
    int s = g * CE;
    int e_end = min(s + CE, nE);
    for (int i = s + tid; i < e_end; i += 1024)
        atomicAdd(&h[row[i] >> 7], 1);
    __syncthreads();
    for (int i = tid; i < NB; i += 1024) table[(size_t)g * NB + i] = h[i];
}

// ---------------- Kernel 2a: per-bucket column scan over the G chunks ----------------
// Block b: thread g holds table[g*NB+b]; block-exclusive-scan over g; total -> tot[b].
__global__ __launch_bounds__(256) void k_scanA(int* __restrict__ table,
                                               int* __restrict__ tot, int NB) {
    const int b = blockIdx.x;
    const int g = threadIdx.x;          // G == 256 == blockDim.x
    const int lane = g & 63, wid = g >> 6;
    int v = table[(size_t)g * NB + b];
    int x = v;
    #pragma unroll
    for (int d = 1; d < 64; d <<= 1) {
        int t = __shfl_up(x, d);
        if (lane >= d) x += t;
    }
    __shared__ int wt[4];
    if (lane == 63) wt[wid] = x;
    __syncthreads();
    int add = 0;
    #pragma unroll
    for (int w = 0; w < 4; ++w) if (w < wid) add += wt[w];
    int incl = x + add;
    table[(size_t)g * NB + b] = incl - v;   // exclusive within-bucket chunk offset
    if (g == 255) tot[b] = incl;            // bucket total
}

// ---------------- Kernel 2b: exclusive scan of bucket totals -> base ----------------
__global__ __launch_bounds__(1024) void k_scanB(const int* __restrict__ tot,
                                                int* __restrict__ base, int NB) {
    __shared__ int t[MAXNB];
    const int b = threadIdx.x;
    int v = (b < NB) ? tot[b] : 0;
    t[b] = v;
    __syncthreads();
    for (int d = 1; d < MAXNB; d <<= 1) {
        int u = (b >= d) ? t[b - d] : 0;
        __syncthreads();
        t[b] += u;
        __syncthreads();
    }
    if (b < NB) base[b] = t[b] - v;
    if (b == NB - 1) base[NB] = t[b];
}

// ---------------- Kernel 3: scatter packed (local_r<<17 | col) into bucket order ----------------
// LDS cursor = chunk offset + bucket base; plain cached stores, no global atomics.
__global__ __launch_bounds__(1024) void k_scatter(const int* __restrict__ row,
                                                  const int* __restrict__ col,
                                                  const int* __restrict__ table,
                                                  const int* __restrict__ base,
                                                  unsigned int* __restrict__ sorted,
                                                  int nE, int CE, int NB) {
    __shared__ int cur[MAXNB];
    const int g = blockIdx.x, tid = threadIdx.x;
    for (int i = tid; i < NB; i += 1024)
        cur[i] = table[(size_t)g * NB + i] + base[i];
    __syncthreads();
    int s = g * CE;
    int e_end = min(s + CE, nE);
    for (int i = s + tid; i < e_end; i += 1024) {
        int r = row[i];
        int c = col[i];
        int b = r >> 7;
        int p = atomicAdd(&cur[b], 1);
        sorted[p] = ((unsigned)(r & 127) << 17) | (unsigned)c;   // col < 131072
    }
}

// ---------------- Kernel 4: per-bucket LDS counting sort + register accumulation + Cholesky ----
__global__ __launch_bounds__(256) void k_node2(const float2* __restrict__ pos,
                                               const unsigned int* __restrict__ sorted,
                                               const int* __restrict__ base,
                                               float* __restrict__ rec, int nN) {
    __shared__ unsigned int ebuf[CAP];
    __shared__ unsigned int ecol[CAP];
    __shared__ int off[BN + 1];
    __shared__ int cur[BN];
    const int b = blockIdx.x, tid = threadIdx.x;
    const int s = base[b], e = base[b + 1];
    const int cntE = min(e - s, CAP);

    for (int i = tid; i < cntE; i += 256) ebuf[i] = sorted[s + i];
    if (tid < BN + 1) off[tid] = 0;
    __syncthreads();
    // count per local node into off[lr+1]
    for (int i = tid; i < cntE; i += 256) atomicAdd(&off[(ebuf[i] >> 17) + 1], 1);
    __syncthreads();
    // inclusive scan of [0, c0, c1, ...] -> off[i] = exclusive prefix of node i, off[BN] = total
    if (tid == 0) {
        int a = 0;
        for (int i = 0; i <= BN; ++i) { a += off[i]; off[i] = a; }
    }
    __syncthreads();
    if (tid < BN) cur[tid] = off[tid];
    __syncthreads();
    for (int i = tid; i < cntE; i += 256) {
        unsigned v = ebuf[i];
        int lr = (int)(v >> 17);
        int p = atomicAdd(&cur[lr], 1);
        ecol[p] = v & 0x1FFFFu;
    }
    __syncthreads();

    if (tid < BN) {
        int n = (b << 7) + tid;
        if (n < nN) {
            float2 pr = pos[n];
            float m[15];
            #pragma unroll
            for (int i = 0; i < 15; ++i) m[i] = 0.0f;
            int j0 = off[tid], j1 = off[tid + 1];
            for (int j = j0; j < j1; ++j) {
                float2 pc = pos[ecol[j]];
                float x = pc.x - pr.x;
                float y = pc.y - pr.y;
                float xy = x * y, xx = x * x, yy = y * y;
                m[0]  += x * x;   m[1]  += x * y;   m[2]  += x * xy;  m[3]  += x * xx;  m[4]  += x * yy;
                m[5]  += y * y;   m[6]  += y * xy;  m[7]  += y * xx;  m[8]  += y * yy;
                m[9]  += xy * xy; m[10] += xy * xx; m[11] += xy * yy;
                m[12] += xx * xx; m[13] += xx * yy;
                m[14] += yy * yy;
            }
            // overflow beyond CAP (statistically never): scan global tail
            for (int j = CAP; j < e - s; ++j) {
                unsigned v = sorted[s + j];
                if ((int)(v >> 17) == tid) {
                    float2 pc = pos[v & 0x1FFFFu];
                    float x = pc.x - pr.x;
                    float y = pc.y - pr.y;
                    float xy = x * y, xx = x * x, yy = y * y;
                    m[0]  += x * x;   m[1]  += x * y;   m[2]  += x * xy;  m[3]  += x * xx;  m[4]  += x * yy;
                    m[5]  += y * y;   m[6]  += y * xy;  m[7]  += y * xx;  m[8]  += y * yy;
                    m[9]  += xy * xy; m[10] += xy * xx; m[11] += xy * yy;
                    m[12] += xx * xx; m[13] += xx * yy;
                    m[14] += yy * yy;
                }
            }

            double A[5][5];
            {
                int idx = 0;
                #pragma unroll
                for (int i = 0; i < 5; ++i) {
                    #pragma unroll
                    for (int j = i; j < 5; ++j) {
                        double v = (double)m[idx++];
                        A[i][j] = v;
                        A[j][i] = v;
                    }
                }
            }
            #pragma unroll
            for (int i = 0; i < 5; ++i) A[i][i] += RIDGE;

            #pragma unroll
            for (int k = 0; k < 5; ++k) {
                double d = A[k][k];
                d = sqrt(fmax(d, 1e-300));
                A[k][k] = d;
                double inv = 1.0 / d;
                #pragma unroll
                for (int i = k + 1; i < 5; ++i) A[i][k] *= inv;
                #pragma unroll
                for (int j = k + 1; j < 5; ++j) {
                    #pragma unroll
                    for (int i = j; i < 5; ++i) A[i][j] -= A[i][k] * A[j][k];
                }
            }
            double bb[5] = {0.0, 0.0, 0.0, 2.0, 2.0};
            double y[5];
            #pragma unroll
            for (int i = 0; i < 5; ++i) {
                double sv = bb[i];
                #pragma unroll
                for (int k = 0; k < 5; ++k) {
                    if (k < i) sv -= A[i][k] * y[k];
                }
                y[i] = sv / A[i][i];
            }
            double xs[5];
            #pragma unroll
            for (int ii = 4; ii >= 0; --ii) {
                double sv = y[ii];
                #pragma unroll
                for (int k = 0; k < 5; ++k) {
                    if (k > ii) sv -= A[k][ii] * xs[k];
                }
                xs[ii] = sv / A[ii][ii];
            }
            float4* rb = (float4*)(rec + (size_t)n * 8);
            rb[0] = make_float4((float)xs[0], (float)xs[1], (float)xs[2], (float)xs[3]);
            rb[1] = make_float4((float)xs[4], pr.x, pr.y, 0.0f);
        }
    }
}

// ---------------- Kernel 5: per-edge weight = <C[row], H>, clipped (overwrites d_out) ----
__global__ __launch_bounds__(256) void k_weights(const float2* __restrict__ pos,
                                                 const int* __restrict__ row,
                                                 const int* __restrict__ col,
                                                 const float* __restrict__ rec,
                                                 float* __restrict__ out,
                                                 int nE) {
    int e = blockIdx.x * blockDim.x + threadIdx.x;
    if (e >= nE) return;
    int r = row[e];
    int c = col[e];
    const float4* rb = (const float4*)(rec + (size_t)r * 8);
    float4 r0 = rb[0];               // C0..C3
    float4 r1 = rb[1];               // C4, pos_r.x, pos_r.y, pad
    float2 pc = pos[c];
    float x = pc.x - r1.y;
    float y = pc.y - r1.z;
    float w = r0.x * x + r0.y * y + r0.z * (x * y) + r0.w * (x * x) + r1.x * (y * y);
    w = fminf(fmaxf(w, -WLIM), WLIM);
    out[e] = w;
}

extern "C" void kernel_launch(void* const* d_in, const int* in_sizes, int n_in,
                              void* d_out, int out_size, void* d_ws, size_t ws_size,
                              hipStream_t stream) {
    const float2* pos = (const float2*)d_in[0];
    const int* ei = (const int*)d_in[1];
    const int nN = in_sizes[0] / 2;   // (N,2) f32
    const int nE = in_sizes[1] / 2;   // (2,E) int32
    const int* row = ei;
    const int* col = ei + nE;

    const int NB = (nN + BN - 1) >> 7;        // buckets of 128 nodes (782)
    const int CE = (nE + G - 1) / G;          // edges per hist/scatter block

    // ws layout: table[G*NB] | tot[NB] | base[NB+1] | pad to 16B | rec[nN*8 floats]
    int* table = (int*)d_ws;
    int* tot = table + (size_t)G * NB;
    int* base = tot + NB;
    size_t roff = (((size_t)G * NB + NB + NB + 1) + 3) & ~(size_t)3;
    float* rec = (float*)((int*)d_ws + roff);

    unsigned int* sorted = (unsigned int*)d_out;  // consumed by k_node2 before k_weights overwrites
    float* out = (float*)d_out;

    k_hist<<<G, 1024, 0, stream>>>(row, table, nE, CE, NB);
    k_scanA<<<NB, 256, 0, stream>>>(table, tot, NB);
    k_scanB<<<1, 1024, 0, stream>>>(tot, base, NB);
    k_scatter<<<G, 1024, 0, stream>>>(row, col, table, base, sorted, nE, CE, NB);
    k_node2<<<NB, 256, 0, stream>>>(pos, sorted, base, rec, nN);
    k_weights<<<(nE + 255) / 256, 256, 0, stream>>>(pos, row, col, rec, out, nE);
}

// Round 9
// 101.967 us; speedup vs baseline: 2.7940x; 1.1740x over previous
//
#include <hip/hip_runtime.h>
#include <math.h>

constexpr float WLIM = 5000.0f;
constexpr double RIDGE = 1e-7;

#define G 256             // edge chunks (one block each in k_sort; one thread each in k_node3)
#define MAXNB 1024        // max buckets (nN up to 131072)
#define BN 128            // nodes per bucket
#define CAP 6144          // LDS edge capacity per bucket in k_node3 (mean 4096, +32 sigma)
#define EBUF_CAP 12544    // LDS edge capacity per chunk in k_sort (nE<=3.21M with G=256)

// ---------------- Kernel 1: fused per-chunk {histogram, scan, counting sort, coalesced dump} ----
// Block g handles edges [g*CE, min((g+1)*CE, nE)). Writes:
//   sorted[g*CE + i]  : chunk's edges grouped by bucket (packed (r&127)<<17 | c)
//   table[g*NBP + b]  : exclusive offset of bucket b within this chunk; [NB] = chunk count
__global__ __launch_bounds__(1024) void k_sort(const int* __restrict__ row,
                                               const int* __restrict__ col,
                                               int* __restrict__ table,
                                               unsigned int* __restrict__ sorted,
                                               int nE, int CE, int NB) {
    __shared__ int h[MAXNB];            // histogram -> cursors
    __shared__ int t[MAXNB];            // scan temp
    __shared__ unsigned int ebuf[EBUF_CAP];
    const int g = blockIdx.x, tid = threadIdx.x;
    const int NBP = NB + 1;
    const int s = g * CE;
    const int e_end = min(s + CE, nE);
    const int cnt = e_end - s;

    for (int i = tid; i < MAXNB; i += 1024) h[i] = 0;
    __syncthreads();
    // pass 1: histogram (LDS int atomics)
    for (int i = s + tid; i < e_end; i += 1024)
        atomicAdd(&h[row[i] >> 7], 1);
    __syncthreads();
    // block-wide Hillis-Steele inclusive scan of h -> t
    int v = h[tid];
    t[tid] = v;
    __syncthreads();
    for (int d = 1; d < MAXNB; d <<= 1) {
        int u = (tid >= d) ? t[tid - d] : 0;
        __syncthreads();
        t[tid] += u;
        __syncthreads();
    }
    // exclusive offsets; write table row; reset cursors
    int excl = t[tid] - v;
    if (tid < NB) {
        table[(size_t)g * NBP + tid] = excl;
        h[tid] = excl;                  // cursor
    }
    if (tid == 0) table[(size_t)g * NBP + NB] = cnt;
    __syncthreads();
    // pass 2: counting sort into LDS
    for (int i = s + tid; i < e_end; i += 1024) {
        int r = row[i];
        int c = col[i];
        int b = r >> 7;
        int p = atomicAdd(&h[b], 1);
        ebuf[p] = ((unsigned)(r & 127) << 17) | (unsigned)c;   // col < 131072
    }
    __syncthreads();
    // coalesced dump
    for (int i = tid; i < cnt; i += 1024)
        sorted[s + i] = ebuf[i];
}

// ---------------- Kernel 2: per-bucket gather of 256 runs + LDS node sort + Cholesky ----
__global__ __launch_bounds__(256) void k_node3(const float2* __restrict__ pos,
                                               const unsigned int* __restrict__ sorted,
                                               const int* __restrict__ table,
                                               float* __restrict__ rec,
                                               int nN, int CE, int NB, int nG) {
    __shared__ unsigned int ebuf[CAP];
    __shared__ unsigned int ecol[CAP];
    __shared__ int off[BN + 1];
    __shared__ int cur[BN];
    __shared__ int goff0[G], gplaced[G], glen[G];
    __shared__ int wt[4];
    __shared__ int ovf;
    const int b = blockIdx.x, tid = threadIdx.x;
    const int NBP = NB + 1;

    // thread tid <-> chunk g: read this chunk's run [off0, off1) for bucket b
    int off0 = 0, len = 0;
    if (tid < nG) {
        const int* trow = table + (size_t)tid * NBP;
        off0 = trow[b];
        len = trow[b + 1] - off0;       // b+1 <= NB valid (stride NB+1)
    }
    // block scan of lens -> LDS start position
    const int lane = tid & 63, wid = tid >> 6;
    int x = len;
    #pragma unroll
    for (int d = 1; d < 64; d <<= 1) {
        int u = __shfl_up(x, d);
        if (lane >= d) x += u;
    }
    if (lane == 63) wt[wid] = x;
    if (tid == 0) ovf = 0;
    __syncthreads();
    int add = 0;
    #pragma unroll
    for (int w = 0; w < 4; ++w) if (w < wid) add += wt[w];
    int mystart = x + add - len;        // exclusive prefix
    int total = 0;
    {
        __shared__ int tot_s;
        if (tid == 255) tot_s = x + add;
        __syncthreads();
        total = tot_s;
    }
    int placed = min(len, max(0, CAP - mystart));
    if (placed < len) atomicOr(&ovf, 1);
    goff0[tid] = off0; gplaced[tid] = placed; glen[tid] = len;
    // copy my run into LDS
    int gbase = tid * CE + off0;
    for (int j = 0; j < placed; ++j)
        ebuf[mystart + j] = sorted[gbase + j];
    if (tid < BN + 1) off[tid] = 0;
    __syncthreads();

    const int cntE = min(total, CAP);
    // count per local node into off[lr+1]
    for (int i = tid; i < cntE; i += 256) atomicAdd(&off[(ebuf[i] >> 17) + 1], 1);
    __syncthreads();
    if (tid == 0) {
        int a = 0;
        for (int i = 0; i <= BN; ++i) { a += off[i]; off[i] = a; }
    }
    __syncthreads();
    if (tid < BN) cur[tid] = off[tid];
    __syncthreads();
    for (int i = tid; i < cntE; i += 256) {
        unsigned v = ebuf[i];
        int lr = (int)(v >> 17);
        int p = atomicAdd(&cur[lr], 1);
        ecol[p] = v & 0x1FFFFu;
    }
    __syncthreads();

    if (tid < BN) {
        int n = (b << 7) + tid;
        if (n < nN) {
            float2 pr = pos[n];
            float m[15];
            #pragma unroll
            for (int i = 0; i < 15; ++i) m[i] = 0.0f;
            int j0 = off[tid], j1 = off[tid + 1];
            for (int j = j0; j < j1; ++j) {
                float2 pc = pos[ecol[j]];
                float x2 = pc.x - pr.x;
                float y2 = pc.y - pr.y;
                float xy = x2 * y2, xx = x2 * x2, yy = y2 * y2;
                m[0]  += x2 * x2;  m[1]  += x2 * y2;  m[2]  += x2 * xy; m[3]  += x2 * xx; m[4]  += x2 * yy;
                m[5]  += y2 * y2;  m[6]  += y2 * xy;  m[7]  += y2 * xx; m[8]  += y2 * yy;
                m[9]  += xy * xy;  m[10] += xy * xx;  m[11] += xy * yy;
                m[12] += xx * xx;  m[13] += xx * yy;
                m[14] += yy * yy;
            }
            // overflow path (statistically never): walk unplaced tail of each run
            if (ovf) {
                for (int g2 = 0; g2 < nG; ++g2) {
                    int base2 = g2 * CE + goff0[g2];
                    for (int j = gplaced[g2]; j < glen[g2]; ++j) {
                        unsigned v = sorted[base2 + j];
                        if ((int)(v >> 17) == tid) {
                            float2 pc = pos[v & 0x1FFFFu];
                            float x2 = pc.x - pr.x;
                            float y2 = pc.y - pr.y;
                            float xy = x2 * y2, xx = x2 * x2, yy = y2 * y2;
                            m[0]  += x2 * x2;  m[1]  += x2 * y2;  m[2]  += x2 * xy; m[3]  += x2 * xx; m[4]  += x2 * yy;
                            m[5]  += y2 * y2;  m[6]  += y2 * xy;  m[7]  += y2 * xx; m[8]  += y2 * yy;
                            m[9]  += xy * xy;  m[10] += xy * xx;  m[11] += xy * yy;
                            m[12] += xx * xx;  m[13] += xx * yy;
                            m[14] += yy * yy;
                        }
                    }
                }
            }

            double A[5][5];
            {
                int idx = 0;
                #pragma unroll
                for (int i = 0; i < 5; ++i) {
                    #pragma unroll
                    for (int j = i; j < 5; ++j) {
                        double vv = (double)m[idx++];
                        A[i][j] = vv;
                        A[j][i] = vv;
                    }
                }
            }
            #pragma unroll
            for (int i = 0; i < 5; ++i) A[i][i] += RIDGE;

            #pragma unroll
            for (int k = 0; k < 5; ++k) {
                double d = A[k][k];
                d = sqrt(fmax(d, 1e-300));
                A[k][k] = d;
                double inv = 1.0 / d;
                #pragma unroll
                for (int i = k + 1; i < 5; ++i) A[i][k] *= inv;
                #pragma unroll
                for (int j = k + 1; j < 5; ++j) {
                    #pragma unroll
                    for (int i = j; i < 5; ++i) A[i][j] -= A[i][k] * A[j][k];
                }
            }
            double bb[5] = {0.0, 0.0, 0.0, 2.0, 2.0};
            double y[5];
            #pragma unroll
            for (int i = 0; i < 5; ++i) {
                double sv = bb[i];
                #pragma unroll
                for (int k = 0; k < 5; ++k) {
                    if (k < i) sv -= A[i][k] * y[k];
                }
                y[i] = sv / A[i][i];
            }
            double xs[5];
            #pragma unroll
            for (int ii = 4; ii >= 0; --ii) {
                double sv = y[ii];
                #pragma unroll
                for (int k = 0; k < 5; ++k) {
                    if (k > ii) sv -= A[k][ii] * xs[k];
                }
                xs[ii] = sv / A[ii][ii];
            }
            float4* rb = (float4*)(rec + (size_t)n * 8);
            rb[0] = make_float4((float)xs[0], (float)xs[1], (float)xs[2], (float)xs[3]);
            rb[1] = make_float4((float)xs[4], pr.x, pr.y, 0.0f);
        }
    }
}

// ---------------- Kernel 3: per-edge weight = <C[row], H>, clipped (overwrites d_out) ----
__global__ __launch_bounds__(256) void k_weights(const float2* __restrict__ pos,
                                                 const int* __restrict__ row,
                                                 const int* __restrict__ col,
                                                 const float* __restrict__ rec,
                                                 float* __restrict__ out,
                                                 int nE) {
    int e = blockIdx.x * blockDim.x + threadIdx.x;
    if (e >= nE) return;
    int r = row[e];
    int c = col[e];
    const float4* rb = (const float4*)(rec + (size_t)r * 8);
    float4 r0 = rb[0];               // C0..C3
    float4 r1 = rb[1];               // C4, pos_r.x, pos_r.y, pad
    float2 pc = pos[c];
    float x = pc.x - r1.y;
    float y = pc.y - r1.z;
    float w = r0.x * x + r0.y * y + r0.z * (x * y) + r0.w * (x * x) + r1.x * (y * y);
    w = fminf(fmaxf(w, -WLIM), WLIM);
    out[e] = w;
}

extern "C" void kernel_launch(void* const* d_in, const int* in_sizes, int n_in,
                              void* d_out, int out_size, void* d_ws, size_t ws_size,
                              hipStream_t stream) {
    const float2* pos = (const float2*)d_in[0];
    const int* ei = (const int*)d_in[1];
    const int nN = in_sizes[0] / 2;   // (N,2) f32
    const int nE = in_sizes[1] / 2;   // (2,E) int32
    const int* row = ei;
    const int* col = ei + nE;

    const int NB = (nN + BN - 1) >> 7;        // buckets of 128 nodes (782)
    const int CE = (nE + G - 1) / G;          // edges per chunk (12500, <= EBUF_CAP)

    // ws layout: table[G*(NB+1)] | pad to 16B | rec[nN*8 floats]
    int* table = (int*)d_ws;
    size_t roff = (((size_t)G * (NB + 1)) + 3) & ~(size_t)3;
    float* rec = (float*)((int*)d_ws + roff);

    unsigned int* sorted = (unsigned int*)d_out;  // consumed by k_node3 before k_weights overwrites
    float* out = (float*)d_out;

    k_sort<<<G, 1024, 0, stream>>>(row, col, table, sorted, nE, CE, NB);
    k_node3<<<NB, 256, 0, stream>>>(pos, sorted, table, rec, nN, CE, NB, G);
    k_weights<<<(nE + 255) / 256, 256, 0, stream>>>(pos, row, col, rec, out, nE);
}

// Round 10
// 92.524 us; speedup vs baseline: 3.0791x; 1.1021x over previous
//
#include <hip/hip_runtime.h>
#include <math.h>

constexpr float WLIM = 5000.0f;
constexpr double RIDGE = 1e-7;

#define G 256             // edge chunks (one block each in k_sort; one thread each in k_node3)
#define MAXNB 1024        // max buckets (nN up to 131072)
#define BN 128            // nodes per bucket
#define CAP 5120          // LDS edge capacity per bucket in k_node3 (mean 4096, +16 sigma)
#define EBUF_CAP 12544    // LDS edge capacity per chunk in k_sort

// ---------------- Kernel 1: fused per-chunk {histogram, scan, counting sort, coalesced dump} ----
// Block g handles edges [g*CE, min((g+1)*CE, nE)). Writes:
//   sorted[g*CE + i]   : chunk's edges grouped by bucket (packed (r&127)<<17 | c)
//   table[b*G + g]     : TRANSPOSED exclusive offset of bucket b within chunk g; row NB = count
__global__ __launch_bounds__(1024) void k_sort(const int* __restrict__ row,
                                               const int* __restrict__ col,
                                               int* __restrict__ table,
                                               unsigned int* __restrict__ sorted,
                                               int nE, int CE, int NB) {
    __shared__ int h[MAXNB];            // histogram -> cursors
    __shared__ int t[MAXNB];            // scan temp
    __shared__ unsigned int ebuf[EBUF_CAP];
    const int g = blockIdx.x, tid = threadIdx.x;
    const int s = g * CE;
    const int e_end = min(s + CE, nE);
    const int cnt = e_end - s;

    for (int i = tid; i < MAXNB; i += 1024) h[i] = 0;
    __syncthreads();
    for (int i = s + tid; i < e_end; i += 1024)
        atomicAdd(&h[row[i] >> 7], 1);
    __syncthreads();
    // block-wide Hillis-Steele inclusive scan of h -> t
    int v = h[tid];
    t[tid] = v;
    __syncthreads();
    for (int d = 1; d < MAXNB; d <<= 1) {
        int u = (tid >= d) ? t[tid - d] : 0;
        __syncthreads();
        t[tid] += u;
        __syncthreads();
    }
    int excl = t[tid] - v;
    if (tid < NB) {
        table[(size_t)tid * G + g] = excl;   // transposed write
        h[tid] = excl;                       // cursor
    }
    if (tid == 0) table[(size_t)NB * G + g] = cnt;
    __syncthreads();
    // counting sort into LDS
    for (int i = s + tid; i < e_end; i += 1024) {
        int r = row[i];
        int c = col[i];
        int b = r >> 7;
        int p = atomicAdd(&h[b], 1);
        ebuf[p] = ((unsigned)(r & 127) << 17) | (unsigned)c;   // col < 131072
    }
    __syncthreads();
    // coalesced dump
    for (int i = tid; i < cnt; i += 1024)
        sorted[s + i] = ebuf[i];
}

// ---------------- Kernel 2: per-bucket two-pass node sort (23KB LDS) + pair-accumulate + Cholesky ----
__global__ __launch_bounds__(256) void k_node3(const float2* __restrict__ pos,
                                               const unsigned int* __restrict__ sorted,
                                               const int* __restrict__ table,
                                               float* __restrict__ rec,
                                               int nN, int CE, int NB) {
    __shared__ unsigned int ebuf[CAP];   // node-sorted cols
    __shared__ int off[BN + 1];
    __shared__ int cur[BN];
    __shared__ int goff0[G], glen[G];
    const int b = blockIdx.x, tid = threadIdx.x;

    // coalesced transposed-table reads: my chunk's run for this bucket
    int off0 = table[(size_t)b * G + tid];
    int off1 = table[(size_t)(b + 1) * G + tid];   // row NB = chunk count when b == NB-1
    int len = off1 - off0;
    goff0[tid] = off0; glen[tid] = len;
    if (tid < BN + 1) off[tid] = 0;
    __syncthreads();

    // pass 1: count per local node (runs stay in global; L3-warm)
    const int gbase = tid * CE + off0;
    for (int j = 0; j < len; ++j)
        atomicAdd(&off[(sorted[gbase + j] >> 17) + 1], 1);
    __syncthreads();
    // inclusive scan of [0, c0, ...] -> off[i] = exclusive prefix, off[BN] = total
    if (tid == 0) {
        int a = 0;
        for (int i = 0; i <= BN; ++i) { a += off[i]; off[i] = a; }
    }
    __syncthreads();
    const int total = off[BN];
    if (tid < BN) cur[tid] = off[tid];
    __syncthreads();

    const bool fits = (total <= CAP);
    if (fits) {
        // pass 2: re-read runs, place col at final node-sorted slot
        for (int j = 0; j < len; ++j) {
            unsigned v = sorted[gbase + j];
            int p = atomicAdd(&cur[(int)(v >> 17)], 1);
            ebuf[p] = v & 0x1FFFFu;
        }
    }
    __syncthreads();

    // accumulate: 2 threads per node (parity split), shfl_xor combine
    const int node = tid >> 1;
    const int half = tid & 1;
    const int n = (b << 7) + node;
    float m[15];
    #pragma unroll
    for (int i = 0; i < 15; ++i) m[i] = 0.0f;
    float2 pr = make_float2(0.f, 0.f);
    if (n < nN) {
        pr = pos[n];
        if (fits) {
            int j0 = off[node], j1 = off[node + 1];
            for (int j = j0 + half; j < j1; j += 2) {
                float2 pc = pos[ebuf[j]];
                float x = pc.x - pr.x;
                float y = pc.y - pr.y;
                float xy = x * y, xx = x * x, yy = y * y;
                m[0]  += x * x;   m[1]  += x * y;   m[2]  += x * xy;  m[3]  += x * xx;  m[4]  += x * yy;
                m[5]  += y * y;   m[6]  += y * xy;  m[7]  += y * xx;  m[8]  += y * yy;
                m[9]  += xy * xy; m[10] += xy * xx; m[11] += xy * yy;
                m[12] += xx * xx; m[13] += xx * yy;
                m[14] += yy * yy;
            }
        } else {
            // overflow fallback (statistically never): walk all runs, filter by node
            for (int g2 = half; g2 < G; g2 += 2) {
                int base2 = g2 * CE + goff0[g2];
                for (int j = 0; j < glen[g2]; ++j) {
                    unsigned v = sorted[base2 + j];
                    if ((int)(v >> 17) == node) {
                        float2 pc = pos[v & 0x1FFFFu];
                        float x = pc.x - pr.x;
                        float y = pc.y - pr.y;
                        float xy = x * y, xx = x * x, yy = y * y;
                        m[0]  += x * x;   m[1]  += x * y;   m[2]  += x * xy;  m[3]  += x * xx;  m[4]  += x * yy;
                        m[5]  += y * y;   m[6]  += y * xy;  m[7]  += y * xx;  m[8]  += y * yy;
                        m[9]  += xy * xy; m[10] += xy * xx; m[11] += xy * yy;
                        m[12] += xx * xx; m[13] += xx * yy;
                        m[14] += yy * yy;
                    }
                }
            }
        }
    }
    // combine parity halves (pairs are wave-aligned)
    #pragma unroll
    for (int i = 0; i < 15; ++i) m[i] += __shfl_xor(m[i], 1);

    if (half == 0 && n < nN) {
        double A[5][5];
        {
            int idx = 0;
            #pragma unroll
            for (int i = 0; i < 5; ++i) {
                #pragma unroll
                for (int j = i; j < 5; ++j) {
                    double vv = (double)m[idx++];
                    A[i][j] = vv;
                    A[j][i] = vv;
                }
            }
        }
        #pragma unroll
        for (int i = 0; i < 5; ++i) A[i][i] += RIDGE;

        #pragma unroll
        for (int k = 0; k < 5; ++k) {
            double d = A[k][k];
            d = sqrt(fmax(d, 1e-300));
            A[k][k] = d;
            double inv = 1.0 / d;
            #pragma unroll
            for (int i = k + 1; i < 5; ++i) A[i][k] *= inv;
            #pragma unroll
            for (int j = k + 1; j < 5; ++j) {
                #pragma unroll
                for (int i = j; i < 5; ++i) A[i][j] -= A[i][k] * A[j][k];
            }
        }
        double bb[5] = {0.0, 0.0, 0.0, 2.0, 2.0};
        double y[5];
        #pragma unroll
        for (int i = 0; i < 5; ++i) {
            double sv = bb[i];
            #pragma unroll
            for (int k = 0; k < 5; ++k) {
                if (k < i) sv -= A[i][k] * y[k];
            }
            y[i] = sv / A[i][i];
        }
        double xs[5];
        #pragma unroll
        for (int ii = 4; ii >= 0; --ii) {
            double sv = y[ii];
            #pragma unroll
            for (int k = 0; k < 5; ++k) {
                if (k > ii) sv -= A[k][ii] * xs[k];
            }
            xs[ii] = sv / A[ii][ii];
        }
        float4* rb = (float4*)(rec + (size_t)n * 8);
        rb[0] = make_float4((float)xs[0], (float)xs[1], (float)xs[2], (float)xs[3]);
        rb[1] = make_float4((float)xs[4], pr.x, pr.y, 0.0f);
    }
}

// ---------------- Kernel 3: per-edge weight = <C[row], H>, clipped (overwrites d_out) ----
__global__ __launch_bounds__(256) void k_weights(const float2* __restrict__ pos,
                                                 const int* __restrict__ row,
                                                 const int* __restrict__ col,
                                                 const float* __restrict__ rec,
                                                 float* __restrict__ out,
                                                 int nE) {
    int e = blockIdx.x * blockDim.x + threadIdx.x;
    if (e >= nE) return;
    int r = row[e];
    int c = col[e];
    const float4* rb = (const float4*)(rec + (size_t)r * 8);
    float4 r0 = rb[0];               // C0..C3
    float4 r1 = rb[1];               // C4, pos_r.x, pos_r.y, pad
    float2 pc = pos[c];
    float x = pc.x - r1.y;
    float y = pc.y - r1.z;
    float w = r0.x * x + r0.y * y + r0.z * (x * y) + r0.w * (x * x) + r1.x * (y * y);
    w = fminf(fmaxf(w, -WLIM), WLIM);
    out[e] = w;
}

extern "C" void kernel_launch(void* const* d_in, const int* in_sizes, int n_in,
                              void* d_out, int out_size, void* d_ws, size_t ws_size,
                              hipStream_t stream) {
    const float2* pos = (const float2*)d_in[0];
    const int* ei = (const int*)d_in[1];
    const int nN = in_sizes[0] / 2;   // (N,2) f32
    const int nE = in_sizes[1] / 2;   // (2,E) int32
    const int* row = ei;
    const int* col = ei + nE;

    const int NB = (nN + BN - 1) >> 7;        // buckets of 128 nodes (782)
    const int CE = (nE + G - 1) / G;          // edges per chunk (12500 <= EBUF_CAP)

    // ws layout: table[(NB+1)*G] | pad to 16B | rec[nN*8 floats]
    int* table = (int*)d_ws;
    size_t roff = (((size_t)(NB + 1) * G) + 3) & ~(size_t)3;
    float* rec = (float*)((int*)d_ws + roff);

    unsigned int* sorted = (unsigned int*)d_out;  // consumed by k_node3 before k_weights overwrites
    float* out = (float*)d_out;

    k_sort<<<G, 1024, 0, stream>>>(row, col, table, sorted, nE, CE, NB);
    k_node3<<<NB, 256, 0, stream>>>(pos, sorted, table, rec, nN, CE, NB);
    k_weights<<<(nE + 255) / 256, 256, 0, stream>>>(pos, row, col, rec, out, nE);
}